// Round 2
// baseline (176.007 us; speedup 1.0000x reference)
//
#include <hip/hip_runtime.h>

#define D 128
#define N_HALF 4096
#define M_ROWS 8192
#define R_TILES 64          // 8192 / 128
#define N_TILES 2080        // 64*65/2 upper-triangular blocks

typedef __attribute__((ext_vector_type(8))) short short8;   // 8 x bf16 (4 VGPRs)
typedef __attribute__((ext_vector_type(4))) float float4v;  // 4 x f32 acc

static __device__ __forceinline__ unsigned short f2bf(float f) {
    unsigned int u = __float_as_uint(f);
    unsigned int r = (u + 0x7fffu + ((u >> 16) & 1u)) >> 16;  // RNE
    return (unsigned short)r;
}

// ---- P1: per-row sum of squares (one wave per row) ----
__global__ void p1_rowsq(const float* __restrict__ src, const float* __restrict__ tgt,
                         float* __restrict__ rowsq) {
    int wave = threadIdx.x >> 6, lane = threadIdx.x & 63;
    int r = blockIdx.x * 4 + wave;
    const float* Xr = (r < N_HALF) ? src + (size_t)r * D : tgt + (size_t)(r - N_HALF) * D;
    float f0 = Xr[lane], f1 = Xr[lane + 64];
    float s = f0 * f0 + f1 * f1;
    #pragma unroll
    for (int off = 32; off; off >>= 1) s += __shfl_down(s, off);
    if (lane == 0) rowsq[r] = s;
}

// ---- P2: partial column sums (128 blocks x 64 rows) ----
__global__ void p2_colpart(const float* __restrict__ src, const float* __restrict__ tgt,
                           float* __restrict__ colpart) {
    int b = blockIdx.x;
    int col = threadIdx.x & 127, half = threadIdx.x >> 7;
    const float* X = (b < 64) ? src + (size_t)(b * 64) * D : tgt + (size_t)((b - 64) * 64) * D;
    float part = 0.f;
    for (int i = 0; i < 32; ++i) part += X[(size_t)(2 * i + half) * D + col];
    __shared__ float cp[2][128];
    cp[half][col] = part;
    __syncthreads();
    if (threadIdx.x < 128) colpart[b * 128 + threadIdx.x] = cp[0][threadIdx.x] + cp[1][threadIdx.x];
}

// ---- P3: bandwidth constant + zero the fp64 accumulator ----
__global__ void p3_consts(const float* __restrict__ rowsq, const float* __restrict__ colpart,
                          float* __restrict__ wsf, double* __restrict__ acc) {
    int tid = threadIdx.x;
    __shared__ float red[8];
    float s = 0.f;
    for (int i = 0; i < 32; ++i) s += rowsq[tid + 256 * i];
    #pragma unroll
    for (int off = 32; off; off >>= 1) s += __shfl_down(s, off);
    if ((tid & 63) == 0) red[tid >> 6] = s;
    __syncthreads();
    float sumsq = red[0] + red[1] + red[2] + red[3];

    float v = 0.f;
    if (tid < 128) {
        float sd = 0.f;
        for (int b = 0; b < 128; ++b) sd += colpart[b * 128 + tid];
        v = sd * sd;
    }
    __syncthreads();
    #pragma unroll
    for (int off = 32; off; off >>= 1) v += __shfl_down(v, off);
    if ((tid & 63) == 0) red[4 + (tid >> 6)] = v;
    __syncthreads();
    if (tid == 0) {
        double s2 = (double)red[4] + red[5] + red[6] + red[7];
        double sumL2 = 2.0 * 8192.0 * (double)sumsq - 2.0 * s2;
        double bw = sumL2 / (8192.0 * 8192.0 - 8192.0) / 4.0;  // /KERNEL_MUL^(5/2)
        // c4 = -log2(e) / (bw * 2^4); exp(-L2/(bw*2^k)) = exp2(L2*c4)^(2^(4-k))
        wsf[4] = (float)(-1.4426950408889634 / (bw * 16.0));
        *acc = 0.0;
    }
}

// ---- M: tiled gram + fused 5-scale RBF epilogue ----
__global__ __launch_bounds__(256) void mmd_main(const float* __restrict__ src,
                                                const float* __restrict__ tgt,
                                                const float* __restrict__ rowsq,
                                                const float* __restrict__ wsf,
                                                double* __restrict__ acc) {
    __shared__ unsigned short ldsA[128 * D];  // 32 KB
    __shared__ unsigned short ldsB[128 * D];  // 32 KB  (total exactly 64 KB)

    // triangular block index -> (bi <= bj)
    int t = blockIdx.x;
    int bi = (int)((129.0 - sqrt(129.0 * 129.0 - 8.0 * (double)t)) * 0.5);
    auto base = [](int b) { return (b * (129 - b)) >> 1; };
    while (base(bi + 1) <= t) ++bi;
    while (base(bi) > t) --bi;
    int bj = bi + (t - base(bi));

    const int tid = threadIdx.x;
    const float* XA = (bi < 32) ? src + (size_t)bi * 128 * D : tgt + (size_t)(bi - 32) * 128 * D;
    const float* XB = (bj < 32) ? src + (size_t)bj * 128 * D : tgt + (size_t)(bj - 32) * 128 * D;

    // stage both 128x128 tiles as bf16
    #pragma unroll
    for (int i = 0; i < 16; ++i) {
        int idx = i * 256 + tid;  // float4 index
        float4 va = ((const float4*)XA)[idx];
        float4 vb = ((const float4*)XB)[idx];
        ushort4 ua; ua.x = f2bf(va.x); ua.y = f2bf(va.y); ua.z = f2bf(va.z); ua.w = f2bf(va.w);
        ushort4 ub; ub.x = f2bf(vb.x); ub.y = f2bf(vb.y); ub.z = f2bf(vb.z); ub.w = f2bf(vb.w);
        *(ushort4*)&ldsA[idx * 4] = ua;
        *(ushort4*)&ldsB[idx * 4] = ub;
    }
    float c4 = wsf[4];
    __syncthreads();

    const int lane = tid & 63, quad = lane >> 4;
    const int wm = (tid >> 6) & 1, wn = tid >> 7;   // 2x2 wave grid, 64x64 per wave
    const int mrow = lane & 15;

    float4v accf[4][4];
    #pragma unroll
    for (int mt = 0; mt < 4; ++mt)
        #pragma unroll
        for (int nt = 0; nt < 4; ++nt)
            accf[mt][nt] = (float4v){0.f, 0.f, 0.f, 0.f};

    #pragma unroll
    for (int kc = 0; kc < 4; ++kc) {
        const int ko = kc * 32 + quad * 8;
        short8 af[4], bf[4];
        #pragma unroll
        for (int mt = 0; mt < 4; ++mt)
            af[mt] = *(const short8*)&ldsA[(wm * 64 + mt * 16 + mrow) * D + ko];
        #pragma unroll
        for (int nt = 0; nt < 4; ++nt)
            bf[nt] = *(const short8*)&ldsB[(wn * 64 + nt * 16 + mrow) * D + ko];
        #pragma unroll
        for (int mt = 0; mt < 4; ++mt)
            #pragma unroll
            for (int nt = 0; nt < 4; ++nt)
                accf[mt][nt] = __builtin_amdgcn_mfma_f32_16x16x32_bf16(af[mt], bf[nt], accf[mt][nt], 0, 0, 0);
    }

    // epilogue: L2 -> sum of 5 exps (one v_exp + 4 squarings)
    const float* rsqA = rowsq + bi * 128;
    const float* rsqB = rowsq + bj * 128;
    float part = 0.f;
    #pragma unroll
    for (int mt = 0; mt < 4; ++mt) {
        float rA[4];
        #pragma unroll
        for (int r = 0; r < 4; ++r) rA[r] = rsqA[wm * 64 + mt * 16 + quad * 4 + r];
        #pragma unroll
        for (int nt = 0; nt < 4; ++nt) {
            float rB = rsqB[wn * 64 + nt * 16 + mrow];
            float4v d = accf[mt][nt];
            #pragma unroll
            for (int r = 0; r < 4; ++r) {
                float L2 = rA[r] + rB - 2.f * d[r];
                float e1 = __builtin_amdgcn_exp2f(L2 * c4);
                float e2 = e1 * e1, e4 = e2 * e2, e8 = e4 * e4, e16 = e8 * e8;
                part += ((e1 + e2) + (e4 + e8)) + e16;
            }
        }
    }
    #pragma unroll
    for (int off = 32; off; off >>= 1) part += __shfl_down(part, off);
    if (lane == 0) {
        float w = ((bi < 32) == (bj < 32)) ? 1.f : -1.f;  // sign structure of XX+YY-XY-YX
        if (bi != bj) w *= 2.f;                           // symmetric off-diagonal tiles
        atomicAdd(acc, (double)(w * part));
    }
}

// ---- F: scale and emit ----
__global__ void f_final(const double* __restrict__ acc, float* __restrict__ out) {
    out[0] = (float)(acc[0] * (1.0 / (4096.0 * 4096.0)));
}

extern "C" void kernel_launch(void* const* d_in, const int* in_sizes, int n_in,
                              void* d_out, int out_size, void* d_ws, size_t ws_size,
                              hipStream_t stream) {
    const float* src = (const float*)d_in[0];
    const float* tgt = (const float*)d_in[1];
    float* wsf = (float*)d_ws;
    double* acc = (double*)d_ws;         // bytes [0,8): fp64 accumulator
    float* rowsq = wsf + 8;              // 8192 floats
    float* colpart = wsf + 8704;         // 128*128 floats (~100 KB total ws use)

    hipLaunchKernelGGL(p1_rowsq, dim3(2048), dim3(256), 0, stream, src, tgt, rowsq);
    hipLaunchKernelGGL(p2_colpart, dim3(128), dim3(256), 0, stream, src, tgt, colpart);
    hipLaunchKernelGGL(p3_consts, dim3(1), dim3(256), 0, stream, rowsq, colpart, wsf, acc);
    hipLaunchKernelGGL(mmd_main, dim3(N_TILES), dim3(256), 0, stream, src, tgt, rowsq, wsf, acc);
    hipLaunchKernelGGL(f_final, dim3(1), dim3(1), 0, stream, acc, (float*)d_out);
}

// Round 3
// 94.886 us; speedup vs baseline: 1.8549x; 1.8549x over previous
//
#include <hip/hip_runtime.h>

#define D 128
#define N_TILES 2080        // 64*65/2 upper-triangular 128x128 blocks

typedef __attribute__((ext_vector_type(8))) short short8;   // 8 x bf16 (4 VGPRs)
typedef __attribute__((ext_vector_type(4))) float float4v;  // 4 x f32 acc

static __device__ __forceinline__ unsigned short f2bf(float f) {
    unsigned int u = __float_as_uint(f);
    unsigned int r = (u + 0x7fffu + ((u >> 16) & 1u)) >> 16;  // RNE
    return (unsigned short)r;
}

// ---- C1: rowsq (+ optional bf16 convert of X into ws). One wave per row. ----
template <bool STORE>
__global__ void k_rowsq_convert(const float* __restrict__ src, const float* __restrict__ tgt,
                                float* __restrict__ rowsq, unsigned int* __restrict__ xbf) {
    int wave = threadIdx.x >> 6, lane = threadIdx.x & 63;
    int r = blockIdx.x * 4 + wave;
    const float* Xr = (r < 4096) ? src + (size_t)r * D : tgt + (size_t)(r - 4096) * D;
    float2 f = ((const float2*)Xr)[lane];
    float s = f.x * f.x + f.y * f.y;
    if (STORE) {
        unsigned int lo = f2bf(f.x), hi = f2bf(f.y);
        xbf[r * 64 + lane] = lo | (hi << 16);
    }
    #pragma unroll
    for (int off = 32; off; off >>= 1) s += __shfl_down(s, off);
    if (lane == 0) rowsq[r] = s;
}

// ---- C2: partial column sums (for sum(X) closed form of bw) ----
__global__ void p2_colpart(const float* __restrict__ src, const float* __restrict__ tgt,
                           float* __restrict__ colpart) {
    int b = blockIdx.x;
    int col = threadIdx.x & 127, half = threadIdx.x >> 7;
    const float* X = (b < 64) ? src + (size_t)(b * 64) * D : tgt + (size_t)((b - 64) * 64) * D;
    float part = 0.f;
    for (int i = 0; i < 32; ++i) part += X[(size_t)(2 * i + half) * D + col];
    __shared__ float cp[2][128];
    cp[half][col] = part;
    __syncthreads();
    if (threadIdx.x < 128) colpart[b * 128 + threadIdx.x] = cp[0][threadIdx.x] + cp[1][threadIdx.x];
}

// ---- C3: bandwidth constant ----
__global__ void p3_consts(const float* __restrict__ rowsq, const float* __restrict__ colpart,
                          float* __restrict__ wsf) {
    int tid = threadIdx.x;
    __shared__ float red[8];
    float s = 0.f;
    for (int i = 0; i < 32; ++i) s += rowsq[tid + 256 * i];
    #pragma unroll
    for (int off = 32; off; off >>= 1) s += __shfl_down(s, off);
    if ((tid & 63) == 0) red[tid >> 6] = s;
    __syncthreads();
    float sumsq = red[0] + red[1] + red[2] + red[3];

    float v = 0.f;
    if (tid < 128) {
        float sd = 0.f;
        for (int b = 0; b < 128; ++b) sd += colpart[b * 128 + tid];
        v = sd * sd;
    }
    __syncthreads();
    #pragma unroll
    for (int off = 32; off; off >>= 1) v += __shfl_down(v, off);
    if ((tid & 63) == 0) red[4 + (tid >> 6)] = v;
    __syncthreads();
    if (tid == 0) {
        double s2 = (double)red[4] + red[5] + red[6] + red[7];
        double sumL2 = 2.0 * 8192.0 * (double)sumsq - 2.0 * s2;
        double bw = sumL2 / (8192.0 * 8192.0 - 8192.0) / 4.0;  // /KERNEL_MUL^(5/2)
        wsf[4] = (float)(-1.4426950408889634 / (bw * 16.0));   // c4: exp(-L2/(bw*16)) = exp2(L2*c4)
    }
}

// ---- M: tiled gram + fused 5-scale RBF epilogue ----
// LDS layout: 16B chunk c of row r stored at chunk position (c ^ (r&7)) -> bank-conflict-free
// b128 reads AND contiguous global_load_lds deposit (swizzle carried by per-lane global addr).
template <bool BF16WS>
__global__ __launch_bounds__(256, 2) void mmd_main(const float* __restrict__ src,
                                                   const float* __restrict__ tgt,
                                                   const unsigned short* __restrict__ xbf,
                                                   const float* __restrict__ rowsq,
                                                   const float* __restrict__ wsf,
                                                   float* __restrict__ partial) {
    __shared__ unsigned short ldsA[128 * D];  // 32 KB
    __shared__ unsigned short ldsB[128 * D];  // 32 KB (total 64 KB -> 2 blocks/CU)

    // triangular block index -> (bi <= bj)
    int t = blockIdx.x;
    int bi = (int)((129.0 - sqrt(129.0 * 129.0 - 8.0 * (double)t)) * 0.5);
    auto base = [](int b) { return (b * (129 - b)) >> 1; };
    while (base(bi + 1) <= t) ++bi;
    while (base(bi) > t) --bi;
    int bj = bi + (t - base(bi));

    const int tid = threadIdx.x, lane = tid & 63, wv = tid >> 6;
    const int quad = lane >> 4, mrow = lane & 15;

    if (BF16WS) {
        const unsigned short* XA = xbf + (size_t)bi * 128 * D;
        const unsigned short* XB = xbf + (size_t)bj * 128 * D;
        #pragma unroll
        for (int j = 0; j < 8; ++j) {
            int slot = wv * 512 + j * 64 + lane;           // destination 16B slot
            int rr = slot >> 4, sc = slot & 15;
            int cc = sc ^ (rr & 7);                        // which global chunk lands here
            const unsigned short* gA = XA + rr * D + cc * 8;
            const unsigned short* gB = XB + rr * D + cc * 8;
            int lbase = (wv * 512 + j * 64) * 8;           // wave-uniform LDS base (ushort idx)
            __builtin_amdgcn_global_load_lds((const __attribute__((address_space(1))) void*)gA,
                                             (__attribute__((address_space(3))) void*)&ldsA[lbase],
                                             16, 0, 0);
            __builtin_amdgcn_global_load_lds((const __attribute__((address_space(1))) void*)gB,
                                             (__attribute__((address_space(3))) void*)&ldsB[lbase],
                                             16, 0, 0);
        }
    } else {
        const float* XA = (bi < 32) ? src + (size_t)bi * 128 * D : tgt + (size_t)(bi - 32) * 128 * D;
        const float* XB = (bj < 32) ? src + (size_t)bj * 128 * D : tgt + (size_t)(bj - 32) * 128 * D;
        #pragma unroll
        for (int j = 0; j < 8; ++j) {
            int id = j * 256 + tid;                        // global 16B chunk id
            int rr = id >> 4, cc = id & 15;
            const float4* pa = (const float4*)(XA + rr * D + cc * 8);
            const float4* pb = (const float4*)(XB + rr * D + cc * 8);
            float4 a0 = pa[0], a1 = pa[1];
            float4 b0 = pb[0], b1 = pb[1];
            int dst = rr * D + (cc ^ (rr & 7)) * 8;
            union { unsigned short u[8]; uint4 v; } ka, kb;
            ka.u[0] = f2bf(a0.x); ka.u[1] = f2bf(a0.y); ka.u[2] = f2bf(a0.z); ka.u[3] = f2bf(a0.w);
            ka.u[4] = f2bf(a1.x); ka.u[5] = f2bf(a1.y); ka.u[6] = f2bf(a1.z); ka.u[7] = f2bf(a1.w);
            kb.u[0] = f2bf(b0.x); kb.u[1] = f2bf(b0.y); kb.u[2] = f2bf(b0.z); kb.u[3] = f2bf(b0.w);
            kb.u[4] = f2bf(b1.x); kb.u[5] = f2bf(b1.y); kb.u[6] = f2bf(b1.z); kb.u[7] = f2bf(b1.w);
            *(uint4*)&ldsA[dst] = ka.v;
            *(uint4*)&ldsB[dst] = kb.v;
        }
    }
    float c4 = wsf[4];
    __syncthreads();

    const int wm = wv & 1, wn = wv >> 1;  // 2x2 wave grid, 64x64 per wave

    float4v accf[4][4];
    #pragma unroll
    for (int mt = 0; mt < 4; ++mt)
        #pragma unroll
        for (int nt = 0; nt < 4; ++nt)
            accf[mt][nt] = (float4v){0.f, 0.f, 0.f, 0.f};

    const int xkey = (mrow & 7);
    #pragma unroll
    for (int kc = 0; kc < 4; ++kc) {
        const int c = kc * 4 + quad;
        const int co = (c ^ xkey) * 8;
        short8 af[4], bfr[4];
        #pragma unroll
        for (int mt = 0; mt < 4; ++mt)
            af[mt] = *(const short8*)&ldsA[(wm * 64 + mt * 16 + mrow) * D + co];
        #pragma unroll
        for (int nt = 0; nt < 4; ++nt)
            bfr[nt] = *(const short8*)&ldsB[(wn * 64 + nt * 16 + mrow) * D + co];
        #pragma unroll
        for (int mt = 0; mt < 4; ++mt)
            #pragma unroll
            for (int nt = 0; nt < 4; ++nt)
                accf[mt][nt] = __builtin_amdgcn_mfma_f32_16x16x32_bf16(af[mt], bfr[nt], accf[mt][nt], 0, 0, 0);
    }

    // epilogue: L2 -> sum of 5 exps (one v_exp + 4 squarings)
    const float* rsqA = rowsq + bi * 128;
    const float* rsqB = rowsq + bj * 128;
    float part = 0.f;
    #pragma unroll
    for (int mt = 0; mt < 4; ++mt) {
        float rA[4];
        #pragma unroll
        for (int r = 0; r < 4; ++r) rA[r] = rsqA[wm * 64 + mt * 16 + quad * 4 + r];
        #pragma unroll
        for (int nt = 0; nt < 4; ++nt) {
            float rB = rsqB[wn * 64 + nt * 16 + mrow];
            float4v d = accf[mt][nt];
            #pragma unroll
            for (int r = 0; r < 4; ++r) {
                float L2 = rA[r] + rB - 2.f * d[r];
                float e1 = __builtin_amdgcn_exp2f(L2 * c4);
                float e2 = e1 * e1, e4 = e2 * e2, e8 = e4 * e4, e16 = e8 * e8;
                part += ((e1 + e2) + (e4 + e8)) + e16;
            }
        }
    }
    #pragma unroll
    for (int off = 32; off; off >>= 1) part += __shfl_down(part, off);

    __syncthreads();               // tile data no longer needed; reuse ldsA for reduction
    float* red = (float*)ldsA;
    if (lane == 0) red[wv] = part;
    __syncthreads();
    if (tid == 0) {
        float s = (red[0] + red[1]) + (red[2] + red[3]);
        float wgt = ((bi < 32) == (bj < 32)) ? 1.f : -1.f;  // XX/YY vs XY/YX sign
        if (bi != bj) wgt *= 2.f;                           // symmetric off-diagonal tiles
        partial[blockIdx.x] = wgt * s;
    }
}

// ---- F: reduce per-block partials in fp64, scale, emit ----
__global__ void f_final(const float* __restrict__ partial, float* __restrict__ out) {
    int tid = threadIdx.x, lane = tid & 63;
    double s = 0.0;
    for (int i = tid; i < N_TILES; i += 256) s += (double)partial[i];
    #pragma unroll
    for (int off = 32; off; off >>= 1) s += __shfl_down(s, off);
    __shared__ double r4[4];
    if (lane == 0) r4[tid >> 6] = s;
    __syncthreads();
    if (tid == 0)
        out[0] = (float)(((r4[0] + r4[1]) + (r4[2] + r4[3])) * (1.0 / (4096.0 * 4096.0)));
}

extern "C" void kernel_launch(void* const* d_in, const int* in_sizes, int n_in,
                              void* d_out, int out_size, void* d_ws, size_t ws_size,
                              hipStream_t stream) {
    const float* src = (const float*)d_in[0];
    const float* tgt = (const float*)d_in[1];
    float* wsf = (float*)d_ws;
    float* rowsq = wsf + 16;             // 8192
    float* colpart = wsf + 8208;         // 16384
    float* partial = wsf + 24592;        // 2080  (small-ws footprint ~107 KB)
    unsigned int* xbf = (unsigned int*)(wsf + 32768);  // bf16 X copy: 2 MB at byte 128K

    const size_t NEED = 32768u * 4u + 8192u * 128u * 2u;  // 128 KB + 2 MB
    if (ws_size >= NEED) {
        hipLaunchKernelGGL((k_rowsq_convert<true>), dim3(2048), dim3(256), 0, stream, src, tgt, rowsq, xbf);
        hipLaunchKernelGGL(p2_colpart, dim3(128), dim3(256), 0, stream, src, tgt, colpart);
        hipLaunchKernelGGL(p3_consts, dim3(1), dim3(256), 0, stream, rowsq, colpart, wsf);
        hipLaunchKernelGGL((mmd_main<true>), dim3(N_TILES), dim3(256), 0, stream,
                           src, tgt, (const unsigned short*)xbf, rowsq, wsf, partial);
        hipLaunchKernelGGL(f_final, dim3(1), dim3(256), 0, stream, partial, (float*)d_out);
    } else {
        hipLaunchKernelGGL((k_rowsq_convert<false>), dim3(2048), dim3(256), 0, stream, src, tgt, rowsq, xbf);
        hipLaunchKernelGGL(p2_colpart, dim3(128), dim3(256), 0, stream, src, tgt, colpart);
        hipLaunchKernelGGL(p3_consts, dim3(1), dim3(256), 0, stream, rowsq, colpart, wsf);
        hipLaunchKernelGGL((mmd_main<false>), dim3(N_TILES), dim3(256), 0, stream,
                           src, tgt, (const unsigned short*)xbf, rowsq, wsf, partial);
        hipLaunchKernelGGL(f_final, dim3(1), dim3(256), 0, stream, partial, (float*)d_out);
    }
}